// Round 9
// baseline (165.853 us; speedup 1.0000x reference)
//
#include <hip/hip_runtime.h>
#include <hip/hip_bf16.h>
#include <cstdint>
#include <cstddef>

// Problem constants
#define B_ 64
#define S_ 4096
#define D_ 256
#define BM 64                   // rows per block
#define NBLK (B_ * S_ / BM)     // 4096
#define BLKS_PER_B (S_ / BM)    // 64

typedef __attribute__((ext_vector_type(8))) short short8;
typedef __attribute__((ext_vector_type(4))) float f32x4;
typedef __attribute__((ext_vector_type(4))) float f4;

__device__ __forceinline__ short f2bf(float f) {
  union { float f; uint32_t u; } v; v.f = f;
  uint32_t r = v.u + 0x7FFFu + ((v.u >> 16) & 1u);   // RNE
  return (short)(r >> 16);
}

__device__ __forceinline__ float fast_tanh(float z) {
  // tanh(z) = 1 - 2/(e^{2z}+1); overflow-safe
  return 1.0f - 2.0f * __builtin_amdgcn_rcpf(__expf(2.0f * z) + 1.0f);
}

// Kernel 0: Wt[n][k] = bf16(W[k][n]) via LDS tile transpose. grid 16, 1024 thr.
__global__ void k_pack(const float* __restrict__ W, short* __restrict__ wt) {
  __shared__ float tile[64][65];
  int t = blockIdx.x, ti = t >> 2, tj = t & 3;
  int tid = threadIdx.x;
#pragma unroll
  for (int i = 0; i < 4; ++i) {
    int idx = i * 1024 + tid;
    int r = idx >> 6, c = idx & 63;                 // r: k-local, c: n-local
    tile[c][r] = W[(ti * 64 + r) * 256 + tj * 64 + c];
  }
  __syncthreads();
#pragma unroll
  for (int i = 0; i < 4; ++i) {
    int idx = i * 1024 + tid;
    int r = idx >> 6, c = idx & 63;                 // r: n-local, c: k-local
    wt[(tj * 64 + r) * 256 + ti * 64 + c] = f2bf(tile[r][c]);
  }
}

// Kernel 1: fused GEMM(x@W)+tanh+dot(u) -> scores; per-block softmax partials
// (m, l) and context partial. grid NBLK, 256 thr (4 waves).
// B (wt) in REGISTERS per wave (64-col slice, 128 VGPR, static indexing);
// A (x tile, 64x256 bf16) staged once in XOR-swizzled LDS, shared by 4 waves.
// K-loop is barrier-free: 32 ds_read + 128 MFMA per wave, 2 barriers/block.
__global__ __launch_bounds__(256, 2)
void k_scores(const float* __restrict__ x, const short* __restrict__ wt,
              const float* __restrict__ bias, const float* __restrict__ u,
              float* __restrict__ ws_scores, float* __restrict__ ws_m,
              float* __restrict__ ws_l, float* __restrict__ ws_c) {
  __shared__ __align__(16) short lsA[BM * D_];   // 32 KB, XOR-swizzled rows
  __shared__ float score_part[BM][4];
  __shared__ float e_lds[BM];
  __shared__ float red_lds[1];

  const int tid  = threadIdx.x;
  const int bid  = blockIdx.x;
  const int m0   = bid * BM;
  const int lane = tid & 63;
  const int wv   = tid >> 6;       // 0..3 : 64-col slice
  const int cl   = lane & 15;
  const int gr   = lane >> 4;      // 0..3

  // ---- B into registers: col = wv*64 + nf*16 + cl, k = kf*32 + gr*8 .. +7
  short8 b0[8], b1[8], b2[8], b3[8];
  {
    const short* wb = wt + (wv * 64 + cl) * 256 + gr * 8;
#pragma unroll
    for (int kf = 0; kf < 8; ++kf) {
      b0[kf] = *(const short8*)(wb + kf * 32);
      b1[kf] = *(const short8*)(wb + 16 * 256 + kf * 32);
      b2[kf] = *(const short8*)(wb + 32 * 256 + kf * 32);
      b3[kf] = *(const short8*)(wb + 48 * 256 + kf * 32);
    }
  }
  const float bb0 = bias[wv * 64 + cl],      uu0 = u[wv * 64 + cl];
  const float bb1 = bias[wv * 64 + 16 + cl], uu1 = u[wv * 64 + 16 + cl];
  const float bb2 = bias[wv * 64 + 32 + cl], uu2 = u[wv * 64 + 32 + cl];
  const float bb3 = bias[wv * 64 + 48 + cl], uu3 = u[wv * 64 + 48 + cl];

  // ---- stage A: thread owns row=tid>>2, float cols (tid&3)*64 .. +63
  {
    const int srow = tid >> 2;
    const int scol = (tid & 3) * 64;
    const float* xs = x + (size_t)(m0 + srow) * D_ + scol;
    char* wbase = (char*)lsA + srow * 512;
    const int sxor = (srow & 7) << 4;
#pragma unroll
    for (int i = 0; i < 8; ++i) {
      f4 g0 = *(const f4*)(xs + i * 8);
      f4 g1 = *(const f4*)(xs + i * 8 + 4);
      short8 s;
      s[0]=f2bf(g0[0]); s[1]=f2bf(g0[1]); s[2]=f2bf(g0[2]); s[3]=f2bf(g0[3]);
      s[4]=f2bf(g1[0]); s[5]=f2bf(g1[1]); s[6]=f2bf(g1[2]); s[7]=f2bf(g1[3]);
      *(short8*)(wbase + ((scol * 2 + i * 16) ^ sxor)) = s;
    }
  }
  __syncthreads();   // A staged

  // ---- barrier-free K-loop: acc[rf][nf], rows rf*16+gr*4+j, cols wv*64+nf*16+cl
  f32x4 acc[4][4];
#pragma unroll
  for (int i = 0; i < 4; ++i)
#pragma unroll
    for (int j = 0; j < 4; ++j)
      acc[i][j] = (f32x4){0.f, 0.f, 0.f, 0.f};

  const int axor = (cl & 7) << 4;
#pragma unroll
  for (int rfp = 0; rfp < 4; rfp += 2) {
    const char* ar0 = (const char*)lsA + (rfp * 16 + cl) * 512;
    const char* ar1 = ar0 + 16 * 512;
#pragma unroll
    for (int kf = 0; kf < 8; ++kf) {
      const int ko = (kf * 64 + gr * 16) ^ axor;
      short8 a0 = *(const short8*)(ar0 + ko);
      short8 a1 = *(const short8*)(ar1 + ko);
      acc[rfp][0]     = __builtin_amdgcn_mfma_f32_16x16x32_bf16(a0, b0[kf], acc[rfp][0], 0, 0, 0);
      acc[rfp][1]     = __builtin_amdgcn_mfma_f32_16x16x32_bf16(a0, b1[kf], acc[rfp][1], 0, 0, 0);
      acc[rfp][2]     = __builtin_amdgcn_mfma_f32_16x16x32_bf16(a0, b2[kf], acc[rfp][2], 0, 0, 0);
      acc[rfp][3]     = __builtin_amdgcn_mfma_f32_16x16x32_bf16(a0, b3[kf], acc[rfp][3], 0, 0, 0);
      acc[rfp + 1][0] = __builtin_amdgcn_mfma_f32_16x16x32_bf16(a1, b0[kf], acc[rfp + 1][0], 0, 0, 0);
      acc[rfp + 1][1] = __builtin_amdgcn_mfma_f32_16x16x32_bf16(a1, b1[kf], acc[rfp + 1][1], 0, 0, 0);
      acc[rfp + 1][2] = __builtin_amdgcn_mfma_f32_16x16x32_bf16(a1, b2[kf], acc[rfp + 1][2], 0, 0, 0);
      acc[rfp + 1][3] = __builtin_amdgcn_mfma_f32_16x16x32_bf16(a1, b3[kf], acc[rfp + 1][3], 0, 0, 0);
    }
  }

  // ---- epilogue: per-lane col-partials over this wave's 64 cols
#pragma unroll
  for (int rf = 0; rf < 4; ++rf) {
    float p0 = fast_tanh(acc[rf][0][0] + bb0) * uu0 + fast_tanh(acc[rf][1][0] + bb1) * uu1
             + fast_tanh(acc[rf][2][0] + bb2) * uu2 + fast_tanh(acc[rf][3][0] + bb3) * uu3;
    float p1 = fast_tanh(acc[rf][0][1] + bb0) * uu0 + fast_tanh(acc[rf][1][1] + bb1) * uu1
             + fast_tanh(acc[rf][2][1] + bb2) * uu2 + fast_tanh(acc[rf][3][1] + bb3) * uu3;
    float p2 = fast_tanh(acc[rf][0][2] + bb0) * uu0 + fast_tanh(acc[rf][1][2] + bb1) * uu1
             + fast_tanh(acc[rf][2][2] + bb2) * uu2 + fast_tanh(acc[rf][3][2] + bb3) * uu3;
    float p3 = fast_tanh(acc[rf][0][3] + bb0) * uu0 + fast_tanh(acc[rf][1][3] + bb1) * uu1
             + fast_tanh(acc[rf][2][3] + bb2) * uu2 + fast_tanh(acc[rf][3][3] + bb3) * uu3;
#pragma unroll
    for (int m = 1; m < 16; m <<= 1) {
      p0 += __shfl_xor(p0, m);
      p1 += __shfl_xor(p1, m);
      p2 += __shfl_xor(p2, m);
      p3 += __shfl_xor(p3, m);
    }
    if (cl == 0) {
      int r = rf * 16 + gr * 4;
      score_part[r + 0][wv] = p0;
      score_part[r + 1][wv] = p1;
      score_part[r + 2][wv] = p2;
      score_part[r + 3][wv] = p3;
    }
  }
  __syncthreads();   // score_part complete

  if (tid < 64) {
    float s = score_part[tid][0] + score_part[tid][1] +
              score_part[tid][2] + score_part[tid][3];
    float mx = s;
#pragma unroll
    for (int m = 32; m >= 1; m >>= 1) mx = fmaxf(mx, __shfl_xor(mx, m));
    float e = __expf(s - mx);
    e_lds[tid] = e;
    float l = e;
#pragma unroll
    for (int m = 32; m >= 1; m >>= 1) l += __shfl_xor(l, m);
    ws_scores[m0 + tid] = s;
    if (tid == 0) { ws_m[bid] = mx; ws_l[bid] = l; red_lds[0] = mx; }
  }
  __syncthreads();   // e_lds ready

  // context partial: thread owns column d = tid; x tile is L1/L2-hot
  float cacc = 0.f;
  const float* xp = x + (size_t)m0 * D_ + tid;
#pragma unroll 4
  for (int s = 0; s < BM; ++s) cacc = fmaf(e_lds[s], xp[(size_t)s * D_], cacc);
  ws_c[bid * D_ + tid] = cacc;
}

// Kernel 2: per-batch combine of 64 block partials -> context out + (M, L)
__global__ void k_combine(const float* __restrict__ ws_m, const float* __restrict__ ws_l,
                          const float* __restrict__ ws_c, float* __restrict__ out_ctx,
                          float* __restrict__ ws_M, float* __restrict__ ws_L) {
  int b = blockIdx.x, d = threadIdx.x;
  float M = -3.4e38f;
#pragma unroll
  for (int i = 0; i < BLKS_PER_B; ++i) M = fmaxf(M, ws_m[b * BLKS_PER_B + i]);
  float L = 0.f, c = 0.f;
#pragma unroll 4
  for (int i = 0; i < BLKS_PER_B; ++i) {
    float f = __expf(ws_m[b * BLKS_PER_B + i] - M);
    L += ws_l[b * BLKS_PER_B + i] * f;
    c += ws_c[(size_t)(b * BLKS_PER_B + i) * D_ + d] * f;
  }
  out_ctx[b * D_ + d] = c / L;
  if (d == 0) { ws_M[b] = M; ws_L[b] = L; }
}

// Kernel 3: weights[b,s] = exp(score - M_b) / L_b
__global__ void k_weights(const float* __restrict__ ws_scores, const float* __restrict__ ws_M,
                          const float* __restrict__ ws_L, float* __restrict__ out_w) {
  int idx = blockIdx.x * 256 + threadIdx.x;
  int b = idx >> 12;
  out_w[idx] = __expf(ws_scores[idx] - ws_M[b]) / ws_L[b];
}

extern "C" void kernel_launch(void* const* d_in, const int* in_sizes, int n_in,
                              void* d_out, int out_size, void* d_ws, size_t ws_size,
                              hipStream_t stream) {
  (void)in_sizes; (void)n_in; (void)out_size; (void)ws_size;
  const float* x    = (const float*)d_in[0];
  const float* W    = (const float*)d_in[1];
  const float* bias = (const float*)d_in[2];
  const float* u    = (const float*)d_in[3];
  float* out_ctx = (float*)d_out;                 // [64,256]
  float* out_w   = (float*)d_out + B_ * D_;       // [64,4096]

  char* ws = (char*)d_ws;
  short* wt        = (short*)(ws + 0);            // 131072 B
  float* ws_scores = (float*)(ws + 131072);       // 1048576 B
  float* ws_m      = (float*)(ws + 1179648);      // 16384 B
  float* ws_l      = (float*)(ws + 1196032);      // 16384 B
  float* ws_c      = (float*)(ws + 1212416);      // 4194304 B
  float* ws_M      = (float*)(ws + 5406720);      // 256 B
  float* ws_L      = (float*)(ws + 5406976);      // 256 B

  hipLaunchKernelGGL(k_pack, dim3(16), dim3(1024), 0, stream, W, wt);
  hipLaunchKernelGGL(k_scores, dim3(NBLK), dim3(256), 0, stream,
                     x, wt, bias, u, ws_scores, ws_m, ws_l, ws_c);
  hipLaunchKernelGGL(k_combine, dim3(B_), dim3(256), 0, stream,
                     ws_m, ws_l, ws_c, out_ctx, ws_M, ws_L);
  hipLaunchKernelGGL(k_weights, dim3(B_ * S_ / 256), dim3(256), 0, stream,
                     ws_scores, ws_M, ws_L, out_w);
}

// Round 10
// 151.326 us; speedup vs baseline: 1.0960x; 1.0960x over previous
//
#include <hip/hip_runtime.h>
#include <hip/hip_bf16.h>
#include <cstdint>
#include <cstddef>

// Problem constants
#define B_ 64
#define S_ 4096
#define D_ 256
#define BM 64                   // rows per block (2 rg x 32)
#define NBLK (B_ * S_ / BM)     // 4096
#define BLKS_PER_B (S_ / BM)    // 64

typedef __attribute__((ext_vector_type(8))) short short8;
typedef __attribute__((ext_vector_type(4))) float f32x4;
typedef __attribute__((ext_vector_type(4))) float f4;

__device__ __forceinline__ short f2bf(float f) {
  union { float f; uint32_t u; } v; v.f = f;
  uint32_t r = v.u + 0x7FFFu + ((v.u >> 16) & 1u);   // RNE
  return (short)(r >> 16);
}

__device__ __forceinline__ float fast_tanh(float z) {
  // tanh(z) = 1 - 2/(e^{2z}+1); overflow-safe
  return 1.0f - 2.0f * __builtin_amdgcn_rcpf(__expf(2.0f * z) + 1.0f);
}

// Kernel 0: frag-packed Wt: wtp[((stage*2+cg)*8+nf)*64+lane)*8+j] =
// bf16(W[k][n]) with n = cg*128+nf*16+(lane&15), k = stage*32+(lane>>4)*8+j.
// A wave's B-fragment is then 64 lanes x 16B CONTIGUOUS (1KB) in global.
__global__ void k_pack(const float* __restrict__ W, short* __restrict__ wtp) {
  int idx = blockIdx.x * 1024 + threadIdx.x;   // 64 blocks -> 65536 elements
  int n = idx & 255, k = idx >> 8;             // coalesced read of W row k
  int cg = n >> 7, nf = (n >> 4) & 7, cl = n & 15;
  int stage = k >> 5, oct = (k >> 3) & 3, j = k & 7;
  int lane = oct * 16 + cl;
  int out = ((((stage * 2 + cg) * 8 + nf) * 64) + lane) * 8 + j;
  wtp[out] = f2bf(W[k * 256 + n]);
}

// cvt 8 f32 (two f4) -> short8 bf16 via v_cvt_pk_bf16_f32 (RNE)
#define CVT8(DST, LO, HI)                                                     \
  {                                                                           \
    union { uint32_t u[4]; short8 s; } t_;                                    \
    asm("v_cvt_pk_bf16_f32 %0, %1, %2" : "=v"(t_.u[0]) : "v"(LO[0]), "v"(LO[1])); \
    asm("v_cvt_pk_bf16_f32 %0, %1, %2" : "=v"(t_.u[1]) : "v"(LO[2]), "v"(LO[3])); \
    asm("v_cvt_pk_bf16_f32 %0, %1, %2" : "=v"(t_.u[2]) : "v"(HI[0]), "v"(HI[1])); \
    asm("v_cvt_pk_bf16_f32 %0, %1, %2" : "=v"(t_.u[3]) : "v"(HI[2]), "v"(HI[3])); \
    DST = t_.s;                                                               \
  }

// One K-stage (K=32): consume A slot (4 named f4), refill with stage NXT,
// stream 8 B-frags straight from L2 (frag-packed, coalesced), 16 MFMAs.
// No barriers, no LDS, no waitcnt asm — compiler schedules.
#define GSTEP(S, PA, PB, PC, PD, NXT)                                         \
  {                                                                           \
    short8 a0_, a1_;                                                          \
    CVT8(a0_, PA, PB)                                                         \
    CVT8(a1_, PC, PD)                                                         \
    if ((NXT) < 8) {                                                          \
      PA = *(const f4*)(xr0 + (NXT) * 32);                                    \
      PB = *(const f4*)(xr0 + (NXT) * 32 + 4);                                \
      PC = *(const f4*)(xr1 + (NXT) * 32);                                    \
      PD = *(const f4*)(xr1 + (NXT) * 32 + 4);                                \
    }                                                                         \
    const short* wbs_ = wb + (S) * 8192;                                      \
    _Pragma("unroll")                                                         \
    for (int nf_ = 0; nf_ < 8; ++nf_) {                                       \
      short8 b_ = *(const short8*)(wbs_ + nf_ * 512);                         \
      acc[0][nf_] = __builtin_amdgcn_mfma_f32_16x16x32_bf16(a0_, b_, acc[0][nf_], 0, 0, 0); \
      acc[1][nf_] = __builtin_amdgcn_mfma_f32_16x16x32_bf16(a1_, b_, acc[1][nf_], 0, 0, 0); \
    }                                                                         \
  }

// Kernel 1: barrier-free fused GEMM(x@W)+tanh+dot(u); per-block softmax
// partials (m,l) + context partial. grid NBLK, 256 thr = 4 waves (2rg x 2cg),
// wave = 32 rows x 128 cols. A direct global->reg (2-stage prefetch);
// B direct from frag-packed wtp (L2-resident). LDS only for tiny epilogue.
__global__ __launch_bounds__(256, 4)
void k_scores(const float* __restrict__ x, const short* __restrict__ wtp,
              const float* __restrict__ bias, const float* __restrict__ u,
              float* __restrict__ ws_scores, float* __restrict__ ws_m,
              float* __restrict__ ws_l, float* __restrict__ ws_c) {
  __shared__ float score_part[BM][2];
  __shared__ float e_lds[BM];
  __shared__ float red_lds[1];

  const int tid  = threadIdx.x;
  const int bid  = blockIdx.x;
  const int m0   = bid * BM;
  const int lane = tid & 63;
  const int wv   = tid >> 6;       // 0..3
  const int rg   = wv >> 1;        // row group: rows rg*32..+31
  const int cg   = wv & 1;         // col group: cols cg*128..+127
  const int cl   = lane & 15;
  const int gr   = lane >> 4;      // 0..3

  f32x4 acc[2][8];
#pragma unroll
  for (int i = 0; i < 2; ++i)
#pragma unroll
    for (int j = 0; j < 8; ++j)
      acc[i][j] = (f32x4){0.f, 0.f, 0.f, 0.f};

  // A bases: rf=0 row = m0+rg*32+cl, rf=1 row = +16; k-octet gr*8
  const float* xr0 = x + (size_t)(m0 + rg * 32 + cl) * D_ + gr * 8;
  const float* xr1 = xr0 + 16 * D_;
  // B base for this wave's cg, per-lane 16B slot
  const short* wb = wtp + cg * 4096 + lane * 8;

  // A prefetch: slot A = stage 0, slot B = stage 1 (named regs, no arrays)
  f4 A0, A1, A2, A3, B0, B1, B2, B3;
  A0 = *(const f4*)(xr0);      A1 = *(const f4*)(xr0 + 4);
  A2 = *(const f4*)(xr1);      A3 = *(const f4*)(xr1 + 4);
  B0 = *(const f4*)(xr0 + 32); B1 = *(const f4*)(xr0 + 36);
  B2 = *(const f4*)(xr1 + 32); B3 = *(const f4*)(xr1 + 36);

  GSTEP(0, A0, A1, A2, A3, 2)
  GSTEP(1, B0, B1, B2, B3, 3)
  GSTEP(2, A0, A1, A2, A3, 4)
  GSTEP(3, B0, B1, B2, B3, 5)
  GSTEP(4, A0, A1, A2, A3, 6)
  GSTEP(5, B0, B1, B2, B3, 7)
  GSTEP(6, A0, A1, A2, A3, 8)
  GSTEP(7, B0, B1, B2, B3, 8)

  // ---- epilogue: per-wave col-partials over its 128 cols
  float bb[8], uu[8];
#pragma unroll
  for (int nf = 0; nf < 8; ++nf) {
    bb[nf] = bias[cg * 128 + nf * 16 + cl];
    uu[nf] = u[cg * 128 + nf * 16 + cl];
  }
#pragma unroll
  for (int rf = 0; rf < 2; ++rf) {
    float p0 = 0.f, p1 = 0.f, p2 = 0.f, p3 = 0.f;
#pragma unroll
    for (int nf = 0; nf < 8; ++nf) {
      p0 += fast_tanh(acc[rf][nf][0] + bb[nf]) * uu[nf];
      p1 += fast_tanh(acc[rf][nf][1] + bb[nf]) * uu[nf];
      p2 += fast_tanh(acc[rf][nf][2] + bb[nf]) * uu[nf];
      p3 += fast_tanh(acc[rf][nf][3] + bb[nf]) * uu[nf];
    }
#pragma unroll
    for (int m = 1; m < 16; m <<= 1) {
      p0 += __shfl_xor(p0, m);
      p1 += __shfl_xor(p1, m);
      p2 += __shfl_xor(p2, m);
      p3 += __shfl_xor(p3, m);
    }
    if (cl == 0) {
      int r = rg * 32 + rf * 16 + gr * 4;
      score_part[r + 0][cg] = p0;
      score_part[r + 1][cg] = p1;
      score_part[r + 2][cg] = p2;
      score_part[r + 3][cg] = p3;
    }
  }
  __syncthreads();   // score_part complete

  if (tid < 64) {
    float s = score_part[tid][0] + score_part[tid][1];
    ws_scores[m0 + tid] = s;
    float mx = s;
#pragma unroll
    for (int m = 32; m >= 1; m >>= 1) mx = fmaxf(mx, __shfl_xor(mx, m));
    float e = __expf(s - mx);
    e_lds[tid] = e;
    float l = e;
#pragma unroll
    for (int m = 32; m >= 1; m >>= 1) l += __shfl_xor(l, m);
    if (tid == 0) { ws_m[bid] = mx; ws_l[bid] = l; red_lds[0] = mx; }
  }
  __syncthreads();   // e_lds ready

  // context partial: thread owns column d = tid; x tile is L2-hot
  float cacc = 0.f;
  const float* xp = x + (size_t)m0 * D_ + tid;
#pragma unroll 8
  for (int s = 0; s < BM; ++s) cacc = fmaf(e_lds[s], xp[(size_t)s * D_], cacc);
  ws_c[bid * D_ + tid] = cacc;
}

// Kernel 2: per-batch combine of 64 block partials -> context out + (M, L)
__global__ void k_combine(const float* __restrict__ ws_m, const float* __restrict__ ws_l,
                          const float* __restrict__ ws_c, float* __restrict__ out_ctx,
                          float* __restrict__ ws_M, float* __restrict__ ws_L) {
  int b = blockIdx.x, d = threadIdx.x;
  float M = -3.4e38f;
#pragma unroll
  for (int i = 0; i < BLKS_PER_B; ++i) M = fmaxf(M, ws_m[b * BLKS_PER_B + i]);
  float L = 0.f, c = 0.f;
#pragma unroll 4
  for (int i = 0; i < BLKS_PER_B; ++i) {
    float f = __expf(ws_m[b * BLKS_PER_B + i] - M);
    L += ws_l[b * BLKS_PER_B + i] * f;
    c += ws_c[(size_t)(b * BLKS_PER_B + i) * D_ + d] * f;
  }
  out_ctx[b * D_ + d] = c / L;
  if (d == 0) { ws_M[b] = M; ws_L[b] = L; }
}

// Kernel 3: weights[b,s] = exp(score - M_b) / L_b
__global__ void k_weights(const float* __restrict__ ws_scores, const float* __restrict__ ws_M,
                          const float* __restrict__ ws_L, float* __restrict__ out_w) {
  int idx = blockIdx.x * 256 + threadIdx.x;
  int b = idx >> 12;
  out_w[idx] = __expf(ws_scores[idx] - ws_M[b]) / ws_L[b];
}

extern "C" void kernel_launch(void* const* d_in, const int* in_sizes, int n_in,
                              void* d_out, int out_size, void* d_ws, size_t ws_size,
                              hipStream_t stream) {
  (void)in_sizes; (void)n_in; (void)out_size; (void)ws_size;
  const float* x    = (const float*)d_in[0];
  const float* W    = (const float*)d_in[1];
  const float* bias = (const float*)d_in[2];
  const float* u    = (const float*)d_in[3];
  float* out_ctx = (float*)d_out;                 // [64,256]
  float* out_w   = (float*)d_out + B_ * D_;       // [64,4096]

  char* ws = (char*)d_ws;
  short* wtp       = (short*)(ws + 0);            // 131072 B (frag-packed)
  float* ws_scores = (float*)(ws + 131072);       // 1048576 B
  float* ws_m      = (float*)(ws + 1179648);      // 16384 B
  float* ws_l      = (float*)(ws + 1196032);      // 16384 B
  float* ws_c      = (float*)(ws + 1212416);      // 4194304 B
  float* ws_M      = (float*)(ws + 5406720);      // 256 B
  float* ws_L      = (float*)(ws + 5406976);      // 256 B

  hipLaunchKernelGGL(k_pack, dim3(64), dim3(1024), 0, stream, W, wtp);
  hipLaunchKernelGGL(k_scores, dim3(NBLK), dim3(256), 0, stream,
                     x, wtp, bias, u, ws_scores, ws_m, ws_l, ws_c);
  hipLaunchKernelGGL(k_combine, dim3(B_), dim3(256), 0, stream,
                     ws_m, ws_l, ws_c, out_ctx, ws_M, ws_L);
  hipLaunchKernelGGL(k_weights, dim3(B_ * S_ / 256), dim3(256), 0, stream,
                     ws_scores, ws_M, ws_L, out_w);
}

// Round 14
// 111.212 us; speedup vs baseline: 1.4913x; 1.3607x over previous
//
#include <hip/hip_runtime.h>
#include <hip/hip_bf16.h>
#include <cstdint>
#include <cstddef>

// Problem constants
#define B_ 64
#define S_ 4096
#define D_ 256
#define BM 64                   // rows per block (4 waves x 16 rows)
#define BK 32                   // k-step
#define NBLK (B_ * S_ / BM)     // 4096
#define BLKS_PER_B (S_ / BM)    // 64

typedef __attribute__((ext_vector_type(8))) short short8;
typedef __attribute__((ext_vector_type(4))) float f32x4;
typedef __attribute__((ext_vector_type(4))) float f4;

__device__ __forceinline__ short f2bf(float f) {
  union { float f; uint32_t u; } v; v.f = f;
  uint32_t r = v.u + 0x7FFFu + ((v.u >> 16) & 1u);   // RNE
  return (short)(r >> 16);
}

__device__ __forceinline__ float fast_tanh(float z) {
  // tanh(z) = 1 - 2*rcp(e^{2z}+1); overflow-safe; rcp form PASSED R4/R5/R6
  return 1.0f - 2.0f * __builtin_amdgcn_rcpf(__expf(2.0f * z) + 1.0f);
}

__device__ __forceinline__ void gload_lds16(const short* g, short* l) {
  __builtin_amdgcn_global_load_lds(
      (const __attribute__((address_space(1))) int*)(g),
      (__attribute__((address_space(3))) int*)(l), 16, 0, 0);
}

// Kernel 0: Wt[n][k] = bf16(W[k][n]) via LDS tile transpose. grid 16, 1024 thr.
__global__ void k_pack(const float* __restrict__ W, short* __restrict__ wt) {
  __shared__ float tile[64][65];
  int t = blockIdx.x, ti = t >> 2, tj = t & 3;
  int tid = threadIdx.x;
#pragma unroll
  for (int i = 0; i < 4; ++i) {
    int idx = i * 1024 + tid;
    int r = idx >> 6, c = idx & 63;                 // r: k-local, c: n-local
    tile[c][r] = W[(ti * 64 + r) * 256 + tj * 64 + c];
  }
  __syncthreads();
#pragma unroll
  for (int i = 0; i < 4; ++i) {
    int idx = i * 1024 + tid;
    int r = idx >> 6, c = idx & 63;                 // r: n-local, c: k-local
    wt[(tj * 64 + r) * 256 + ti * 64 + c] = f2bf(tile[r][c]);
  }
}

// ---- k_scores helper macros (R8-proven pipeline, NO inline-asm cvt) --------
#define WAITV(N) asm volatile("s_waitcnt vmcnt(" #N ")" ::: "memory")
#define FENCE()  asm volatile("" ::: "memory")

// Stage B k-step KC into lsB[BUF]: 16 KB, 4 x global_load_lds(16B) per thread.
#define STAGE(BUF, KC)                                                        \
  {                                                                           \
    _Pragma("unroll")                                                         \
    for (int i_ = 0; i_ < 4; ++i_) {                                          \
      int c_ = i_ * 256 + tid;                                                \
      int n_ = c_ >> 2, ko_ = (c_ & 3) * 8;                                   \
      gload_lds16(wt + n_ * 256 + (KC) * 32 + ko_, &lsB[BUF][c_ * 8]);        \
    }                                                                         \
  }

// One pipelined K-step (R8 verbatim): stage(K+1), issue A(K+2), counted
// vmcnt, raw barriers, f2bf cvt A(K) (plain C!), 16 MFMAs from lsB[K&1].
#define ITER(KC, VM, SCA, SCB, SLA, SLB, DOSTAGE, DOLOAD)                     \
  {                                                                           \
    if (DOSTAGE) STAGE(((KC) + 1) & 1, (KC) + 1);                             \
    if (DOLOAD) {                                                             \
      SLA = *(const f4*)(xrow + ((KC) + 2) * 32);                             \
      SLB = *(const f4*)(xrow + ((KC) + 2) * 32 + 4);                         \
    }                                                                         \
    WAITV(VM);                                                                \
    asm volatile("s_waitcnt lgkmcnt(0)" ::: "memory");                        \
    __builtin_amdgcn_sched_barrier(0);                                        \
    __builtin_amdgcn_s_barrier();                                             \
    FENCE();                                                                  \
    short8 fr_;                                                               \
    fr_[0]=f2bf(SCA[0]); fr_[1]=f2bf(SCA[1]); fr_[2]=f2bf(SCA[2]); fr_[3]=f2bf(SCA[3]); \
    fr_[4]=f2bf(SCB[0]); fr_[5]=f2bf(SCB[1]); fr_[6]=f2bf(SCB[2]); fr_[7]=f2bf(SCB[3]); \
    _Pragma("unroll")                                                         \
    for (int nf_ = 0; nf_ < 16; ++nf_) {                                      \
      short8 bfr_ = *(const short8*)&lsB[(KC) & 1][(nf_ * 16 + cl) * 32 + gr * 8]; \
      acc[nf_] = __builtin_amdgcn_mfma_f32_16x16x32_bf16(fr_, bfr_, acc[nf_], 0, 0, 0); \
    }                                                                         \
    FENCE();                                                                  \
    __builtin_amdgcn_s_barrier();                                             \
    FENCE();                                                                  \
  }

// Kernel 1: fused GEMM(x@W)+tanh+dot(u) -> scores; per-block softmax partials
// (m, l) and context partial. grid NBLK, 256 thr (4 waves, 16 rows each).
// B double-buffered in LDS, counted-vmcnt pipeline (R8 schedule, proven).
__global__ __launch_bounds__(256, 3)
void k_scores(const float* __restrict__ x, const short* __restrict__ wt,
              const float* __restrict__ bias, const float* __restrict__ u,
              float* __restrict__ ws_scores, float* __restrict__ ws_m,
              float* __restrict__ ws_l, float* __restrict__ ws_c) {
  __shared__ __align__(16) short lsB[2][D_ * BK];   // 2 x 16 KB, linear (64B rows)
  __shared__ __align__(8) float bu[D_ * 2];         // (bias, u) pairs (R8 layout)
  __shared__ float score_lds[BM];
  __shared__ float e_lds[BM];
  __shared__ float red_lds[1];

  const int tid  = threadIdx.x;
  const int bid  = blockIdx.x;
  const int m0   = bid * BM;
  const int lane = tid & 63;
  const int wv   = tid >> 6;       // 0..3 : 16-row group
  const int cl   = lane & 15;
  const int gr   = lane >> 4;      // 0..3

  // (bias,u) first: compiler drains their loads before the ds_write, keeping
  // the vmcnt queue empty when the pipelined loads start.  (R8 verbatim)
  bu[tid * 2]     = bias[tid];
  bu[tid * 2 + 1] = u[tid];

  f32x4 acc[16];
#pragma unroll
  for (int j = 0; j < 16; ++j) acc[j] = (f32x4){0.f, 0.f, 0.f, 0.f};

  const float* xrow = x + (size_t)(m0 + wv * 16 + cl) * D_ + gr * 8;

  // Prologue: queue = A(0)[2], stage(0)[4], A(1)[2]
  f4 s0a, s0b, s1a, s1b, s2a, s2b;
  s0a = *(const f4*)(xrow);       s0b = *(const f4*)(xrow + 4);
  STAGE(0, 0);
  s1a = *(const f4*)(xrow + 32);  s1b = *(const f4*)(xrow + 36);

  // Steady state: 8 outstanding (4 stage + 2+2 A) stay in flight across waits.
  ITER(0, 8, s0a, s0b, s2a, s2b, 1, 1)
  ITER(1, 8, s1a, s1b, s0a, s0b, 1, 1)
  ITER(2, 8, s2a, s2b, s1a, s1b, 1, 1)
  ITER(3, 8, s0a, s0b, s2a, s2b, 1, 1)
  ITER(4, 8, s1a, s1b, s0a, s0b, 1, 1)
  ITER(5, 8, s2a, s2b, s1a, s1b, 1, 1)
  ITER(6, 6, s0a, s0b, s0a, s0b, 1, 0)
  ITER(7, 0, s1a, s1b, s0a, s0b, 0, 0)

  // Epilogue: score[row] = sum_n tanh(acc[row][n] + b[n]) * u[n]
  float p0 = 0.f, p1 = 0.f, p2 = 0.f, p3 = 0.f;
#pragma unroll
  for (int nf = 0; nf < 16; ++nf) {
    float bb = bu[(nf * 16 + cl) * 2];
    float uu = bu[(nf * 16 + cl) * 2 + 1];
    p0 += fast_tanh(acc[nf][0] + bb) * uu;
    p1 += fast_tanh(acc[nf][1] + bb) * uu;
    p2 += fast_tanh(acc[nf][2] + bb) * uu;
    p3 += fast_tanh(acc[nf][3] + bb) * uu;
  }
#pragma unroll
  for (int m = 1; m < 16; m <<= 1) {
    p0 += __shfl_xor(p0, m);
    p1 += __shfl_xor(p1, m);
    p2 += __shfl_xor(p2, m);
    p3 += __shfl_xor(p3, m);
  }
  if (cl == 0) {
    int r = wv * 16 + gr * 4;
    score_lds[r + 0] = p0;
    score_lds[r + 1] = p1;
    score_lds[r + 2] = p2;
    score_lds[r + 3] = p3;
    ws_scores[m0 + r + 0] = p0;
    ws_scores[m0 + r + 1] = p1;
    ws_scores[m0 + r + 2] = p2;
    ws_scores[m0 + r + 3] = p3;
  }
  __syncthreads();
  // block max over 64 scores (wave 0)
  if (tid < 64) {
    float v = score_lds[tid];
#pragma unroll
    for (int m = 32; m >= 1; m >>= 1) v = fmaxf(v, __shfl_xor(v, m));
    if (tid == 0) red_lds[0] = v;
  }
  __syncthreads();
  float mb = red_lds[0];
  if (tid < BM) e_lds[tid] = __expf(score_lds[tid] - mb);
  __syncthreads();
  if (tid < 64) {
    float v = e_lds[tid];
#pragma unroll
    for (int m = 32; m >= 1; m >>= 1) v += __shfl_xor(v, m);
    if (tid == 0) { ws_m[bid] = mb; ws_l[bid] = v; }
  }
  // context partial: thread owns column d = tid; x tile is L1/L2-hot
  float cacc = 0.f;
  const float* xp = x + (size_t)m0 * D_ + tid;
#pragma unroll 4
  for (int s = 0; s < BM; ++s) cacc = fmaf(e_lds[s], xp[(size_t)s * D_], cacc);
  ws_c[bid * D_ + tid] = cacc;
}

// Kernel 2 (fused combine+weights): grid B_ (64), 1024 thr.
// Wave 0: M, L, rescale factors -> LDS. 256 thr: context out. All: weights.
__global__ __launch_bounds__(1024)
void k_epi(const float* __restrict__ ws_m, const float* __restrict__ ws_l,
           const float* __restrict__ ws_c, const float* __restrict__ ws_scores,
           float* __restrict__ out_ctx, float* __restrict__ out_w) {
  __shared__ float fac[BLKS_PER_B];
  __shared__ float MLs[2];
  const int b = blockIdx.x, tid = threadIdx.x;

  if (tid < 64) {
    float m = ws_m[b * BLKS_PER_B + tid];
    float l = ws_l[b * BLKS_PER_B + tid];
    float M = m;
#pragma unroll
    for (int o = 32; o >= 1; o >>= 1) M = fmaxf(M, __shfl_xor(M, o));
    float f = __expf(m - M);
    fac[tid] = f;
    float L = l * f;
#pragma unroll
    for (int o = 32; o >= 1; o >>= 1) L += __shfl_xor(L, o);
    if (tid == 0) { MLs[0] = M; MLs[1] = L; }
  }
  __syncthreads();
  const float M = MLs[0], L = MLs[1];
  const float invL = 1.0f / L;

  if (tid < D_) {
    float c = 0.f;
#pragma unroll 8
    for (int i = 0; i < BLKS_PER_B; ++i)
      c = fmaf(fac[i], ws_c[(size_t)(b * BLKS_PER_B + i) * D_ + tid], c);
    out_ctx[b * D_ + tid] = c * invL;
  }
#pragma unroll
  for (int r = 0; r < 4; ++r) {
    int s = r * 1024 + tid;
    out_w[b * S_ + s] = __expf(ws_scores[b * S_ + s] - M) * invL;
  }
}

extern "C" void kernel_launch(void* const* d_in, const int* in_sizes, int n_in,
                              void* d_out, int out_size, void* d_ws, size_t ws_size,
                              hipStream_t stream) {
  (void)in_sizes; (void)n_in; (void)out_size; (void)ws_size;
  const float* x    = (const float*)d_in[0];
  const float* W    = (const float*)d_in[1];
  const float* bias = (const float*)d_in[2];
  const float* u    = (const float*)d_in[3];
  float* out_ctx = (float*)d_out;                 // [64,256]
  float* out_w   = (float*)d_out + B_ * D_;       // [64,4096]

  char* ws = (char*)d_ws;
  short* wt        = (short*)(ws + 0);            // 131072 B
  float* ws_scores = (float*)(ws + 131072);       // 1048576 B
  float* ws_m      = (float*)(ws + 1179648);      // 16384 B
  float* ws_l      = (float*)(ws + 1196032);      // 16384 B
  float* ws_c      = (float*)(ws + 1212416);      // 4194304 B

  hipLaunchKernelGGL(k_pack, dim3(16), dim3(1024), 0, stream, W, wt);
  hipLaunchKernelGGL(k_scores, dim3(NBLK), dim3(256), 0, stream,
                     x, wt, bias, u, ws_scores, ws_m, ws_l, ws_c);
  hipLaunchKernelGGL(k_epi, dim3(B_), dim3(1024), 0, stream,
                     ws_m, ws_l, ws_c, ws_scores, out_ctx, out_w);
}